// Round 10
// baseline (263.384 us; speedup 1.0000x reference)
//
#include <hip/hip_runtime.h>
#include <stdint.h>

// Quant3Linear GEMV: y = x @ (scales.T * unpack3(qweight) - zeros.T) + bias
//   x: (1, 8192) f32 | qweight: (768, 28672) i32 | scales,zeros: (28672,1) | bias: (28672,)
// Decomposition: y[o] = scales[o]*dot(x, q[:,o]) - zeros[o]*sum(x) + bias[o]
//
// R10: MEASUREMENT ROUND. Kernel identical to R9 (142.8us, passed). The
// launch enqueues 4 extra dummy copies (atomics into d_ws, correctness
// unaffected) before the real one: dummy#1 runs cold (as the old real launch
// did), dummies #2-4 + real run L3-hot. So dur - 142.8 = 4 x T_hot -- an
// amplified measurement of the kernel's hot time, which the top-5 counter
// cutoff has hidden all session. Discriminates:
//   T_hot ~ 30-35us -> kernel NOT memory-bound, unknown issue cost (attack
//                      instruction stream next);
//   T_hot ~ 12-17us -> hot kernel at issue floor; cold excess = poison-forced
//                      cold-memory path -> write ceiling arithmetic, ROOFLINE.
// History: R1/R2 SPLIT=64+unroll regressed (spill); latency levers neutral
//   (R1 TLP, R3 prefetch); VALU levers neutral (R4 pk, R5 magic); balance
//   neutral (R6); cooperative launch fails capture (R7); fences toxic (R8);
//   fusion/dispatch-count neutral (R9).

typedef float v2f __attribute__((ext_vector_type(2)));

constexpr int O_FEAT  = 28672;
constexpr int IN_FEAT = 8192;
constexpr int NGROUP  = IN_FEAT / 32;   // 256 groups (3 packed int32 rows each)
constexpr int SPLIT   = 32;             // split-K factor
constexpr int GPB     = NGROUP / SPLIT; // 8 groups per thread
constexpr int O4      = O_FEAT / 4;     // uint4 columns per packed row
constexpr int NBX     = O4 / 64;        // 112 column groups (256 cols each)

// Unpack one column-group (32 3-bit codes in w0,w1,w2; GPTQ packing) and
// accumulate dot with xv[0..15] (f32 pairs). Pair-structured so each pair is
// one v_pk_fma_f32; two v2f chains (a0,a1) cover FMA latency.
__device__ __forceinline__ void dot_group_pk(uint32_t w0, uint32_t w1, uint32_t w2,
                                             const v2f xv[16], v2f& acc) {
  v2f a0 = acc, a1 = {0.f, 0.f};
  #pragma unroll
  for (int t = 0; t < 5; ++t) {   // elements 0..9: w0 bits 3j
    v2f q = { (float)((w0 >> (6 * t)) & 7u), (float)((w0 >> (6 * t + 3)) & 7u) };
    (t & 1 ? a1 : a0) += xv[t] * q;
  }
  { // elements 10 (split w0/w1) and 11 (w1 bit 1)
    v2f q = { (float)((w0 >> 30) | ((w1 & 1u) << 2)), (float)((w1 >> 1) & 7u) };
    a1 += xv[5] * q;
  }
  #pragma unroll
  for (int t = 0; t < 4; ++t) {   // elements 12..19: w1 bits 4+3j
    v2f q = { (float)((w1 >> (4 + 6 * t)) & 7u), (float)((w1 >> (7 + 6 * t)) & 7u) };
    (t & 1 ? a1 : a0) += xv[6 + t] * q;
  }
  { // elements 20 (w1 bit 28) and 21 (split w1/w2)
    v2f q = { (float)((w1 >> 28) & 7u), (float)((w1 >> 31) | ((w2 & 3u) << 1)) };
    a0 += xv[10] * q;
  }
  #pragma unroll
  for (int t = 0; t < 5; ++t) {   // elements 22..31: w2 bits 2+3j
    v2f q = { (float)((w2 >> (2 + 6 * t)) & 7u), (float)((w2 >> (5 + 6 * t)) & 7u) };
    (t & 1 ? a1 : a0) += xv[11 + t] * q;
  }
  acc = a0 + a1;
}

__global__ __launch_bounds__(64) void q3_onepass(const float* __restrict__ x,
                                                 const uint4* __restrict__ qw4,
                                                 const float* __restrict__ scales,
                                                 const float* __restrict__ zeros,
                                                 const float* __restrict__ bias,
                                                 float* __restrict__ out) {
  const int tcol4 = blockIdx.x * 64 + threadIdx.x;   // index in units of 4 columns
  const int g0    = blockIdx.y * GPB;
  const uint4* qp = qw4 + (size_t)(3 * g0) * O4 + tcol4;

  // ---- Phase 1: split-K partial (identical to R6) ----
  __shared__ float xs[GPB * 32];
  const float4 xt = reinterpret_cast<const float4*>(x + g0 * 32)[threadIdx.x];
  reinterpret_cast<float4*>(xs)[threadIdx.x] = xt;

  v2f acc0 = {0.f, 0.f}, acc1 = {0.f, 0.f}, acc2 = {0.f, 0.f}, acc3 = {0.f, 0.f};

  // Rolled loop, depth-1 qweight prefetch (last iter re-loads own rows: L1 hit).
  uint4 na = qp[0], nb = qp[O4], nc = qp[2 * O4];
  for (int g = 0; g < GPB; ++g) {
    const uint4 wa = na, wb = nb, wc = nc;
    qp += (g < GPB - 1) ? 3 * O4 : 0;
    na = qp[0]; nb = qp[O4]; nc = qp[2 * O4];

    v2f xv[16];
    const float4* s4 = reinterpret_cast<const float4*>(&xs[g * 32]);
    #pragma unroll
    for (int u = 0; u < 8; ++u) {
      float4 t = s4[u];
      xv[2 * u]     = v2f{t.x, t.y};
      xv[2 * u + 1] = v2f{t.z, t.w};
    }

    dot_group_pk(wa.x, wb.x, wc.x, xv, acc0);  // 4 independent chains
    dot_group_pk(wa.y, wb.y, wc.y, xv, acc1);
    dot_group_pk(wa.z, wb.z, wc.z, xv, acc2);
    dot_group_pk(wa.w, wb.w, wc.w, xv, acc3);
  }

  float4 r = make_float4(acc0.x + acc0.y, acc1.x + acc1.y,
                         acc2.x + acc2.y, acc3.x + acc3.y);

  // ---- Epilogue: scale and accumulate directly into out (fence-free) ----
  const float4 sc = reinterpret_cast<const float4*>(scales)[tcol4];
  float4 contrib;
  contrib.x = sc.x * r.x;
  contrib.y = sc.y * r.y;
  contrib.z = sc.z * r.z;
  contrib.w = sc.w * r.w;

  if (blockIdx.y == 0) {
    // This block folds in the constant term: bias - zeros * sum(x).
    float s = 0.f;
    const float4* xall = reinterpret_cast<const float4*>(x);
    #pragma unroll
    for (int i = 0; i < (IN_FEAT / 4) / 64; ++i) {   // 32 float4 per lane
      float4 t = xall[i * 64 + threadIdx.x];
      s += (t.x + t.y) + (t.z + t.w);
    }
    #pragma unroll
    for (int off = 32; off > 0; off >>= 1) s += __shfl_xor(s, off, 64);
    const float S = s;                               // all lanes hold the total
    const float4 zr = reinterpret_cast<const float4*>(zeros)[tcol4];
    const float4 bi = reinterpret_cast<const float4*>(bias)[tcol4];
    contrib.x += bi.x - zr.x * S;
    contrib.y += bi.y - zr.y * S;
    contrib.z += bi.z - zr.z * S;
    contrib.w += bi.w - zr.w * S;
  }

  float* op = out + 4 * (size_t)tcol4;
  atomicAdd(op + 0, contrib.x);
  atomicAdd(op + 1, contrib.y);
  atomicAdd(op + 2, contrib.z);
  atomicAdd(op + 3, contrib.w);
}

extern "C" void kernel_launch(void* const* d_in, const int* in_sizes, int n_in,
                              void* d_out, int out_size, void* d_ws, size_t ws_size,
                              hipStream_t stream) {
  const float* x      = (const float*)d_in[0];
  const uint4* qw4    = (const uint4*)d_in[1];
  const float* scales = (const float*)d_in[2];
  const float* zeros  = (const float*)d_in[3];
  const float* bias   = (const float*)d_in[4];
  float*       out    = (float*)d_out;
  float*       dummy  = (float*)d_ws;   // 114 KB scratch target for dummy runs

  // 4 dummy launches (#1 cold, #2-4 hot) + real launch (hot).
  // dur - 142.8us = 4 x T_hot.
  for (int i = 0; i < 4; ++i)
    q3_onepass<<<dim3(NBX, SPLIT), dim3(64), 0, stream>>>(x, qw4, scales, zeros,
                                                          bias, dummy);
  q3_onepass<<<dim3(NBX, SPLIT), dim3(64), 0, stream>>>(x, qw4, scales, zeros,
                                                        bias, out);
}

// Round 11
// 223.191 us; speedup vs baseline: 1.1801x; 1.1801x over previous
//
#include <hip/hip_runtime.h>
#include <stdint.h>

// Quant3Linear GEMV: y = x @ (scales.T * unpack3(qweight) - zeros.T) + bias
//   x: (1, 8192) f32 | qweight: (768, 28672) i32 | scales,zeros: (28672,1) | bias: (28672,)
// Decomposition: y[o] = scales[o]*dot(x, q[:,o]) - zeros[o]*sum(x) + bias[o]
//
// R11: MEASUREMENT ROUND 2 (kernel body identical to R9/R10). The 5 repeats
// are folded into ONE dispatch via blockIdx.z (z<4 -> dummy out in d_ws,
// z==4 -> real out). Purpose:
//   1. ~150us dispatch finally EXCEEDS the 51us fill cutoff -> first rocprof
//      counters ever for this kernel (VALUBusy / Occupancy / FETCH).
//   2. Occupancy rises 14 -> ~32 waves/CU: a clean 5x-deep TLP test
//      (R1's 2x test was spill-confounded).
// Pre-committed readout:
//   dur ~250-265 & VALUBusy>70% -> issue-bound, cut real insts (SGPR-x FMA);
//   dur ~250-265 & VALUBusy<40% -> per-wave stalls, target lgkm/vmem waits;
//   dur ~150-185                -> TLP-bound, deepen split-K (rolled loop).
// History: R10 amplification: T_hot ~= 30us == T_cold -> NOT memory-bound
//   (consistent with R1/R3/R4/R5/R6/R9 all neutral); fences toxic (R8);
//   cooperative launch fails capture (R7).

typedef float v2f __attribute__((ext_vector_type(2)));

constexpr int O_FEAT  = 28672;
constexpr int IN_FEAT = 8192;
constexpr int NGROUP  = IN_FEAT / 32;   // 256 groups (3 packed int32 rows each)
constexpr int SPLIT   = 32;             // split-K factor
constexpr int GPB     = NGROUP / SPLIT; // 8 groups per thread
constexpr int O4      = O_FEAT / 4;     // uint4 columns per packed row
constexpr int NBX     = O4 / 64;        // 112 column groups (256 cols each)
constexpr int NREP    = 5;              // amplification layers (z)

// Unpack one column-group (32 3-bit codes in w0,w1,w2; GPTQ packing) and
// accumulate dot with xv[0..15] (f32 pairs). Pair-structured so each pair is
// one v_pk_fma_f32; two v2f chains (a0,a1) cover FMA latency.
__device__ __forceinline__ void dot_group_pk(uint32_t w0, uint32_t w1, uint32_t w2,
                                             const v2f xv[16], v2f& acc) {
  v2f a0 = acc, a1 = {0.f, 0.f};
  #pragma unroll
  for (int t = 0; t < 5; ++t) {   // elements 0..9: w0 bits 3j
    v2f q = { (float)((w0 >> (6 * t)) & 7u), (float)((w0 >> (6 * t + 3)) & 7u) };
    (t & 1 ? a1 : a0) += xv[t] * q;
  }
  { // elements 10 (split w0/w1) and 11 (w1 bit 1)
    v2f q = { (float)((w0 >> 30) | ((w1 & 1u) << 2)), (float)((w1 >> 1) & 7u) };
    a1 += xv[5] * q;
  }
  #pragma unroll
  for (int t = 0; t < 4; ++t) {   // elements 12..19: w1 bits 4+3j
    v2f q = { (float)((w1 >> (4 + 6 * t)) & 7u), (float)((w1 >> (7 + 6 * t)) & 7u) };
    (t & 1 ? a1 : a0) += xv[6 + t] * q;
  }
  { // elements 20 (w1 bit 28) and 21 (split w1/w2)
    v2f q = { (float)((w1 >> 28) & 7u), (float)((w1 >> 31) | ((w2 & 3u) << 1)) };
    a0 += xv[10] * q;
  }
  #pragma unroll
  for (int t = 0; t < 5; ++t) {   // elements 22..31: w2 bits 2+3j
    v2f q = { (float)((w2 >> (2 + 6 * t)) & 7u), (float)((w2 >> (5 + 6 * t)) & 7u) };
    (t & 1 ? a1 : a0) += xv[11 + t] * q;
  }
  acc = a0 + a1;
}

__global__ __launch_bounds__(64) void q3_onepass(const float* __restrict__ x,
                                                 const uint4* __restrict__ qw4,
                                                 const float* __restrict__ scales,
                                                 const float* __restrict__ zeros,
                                                 const float* __restrict__ bias,
                                                 float* __restrict__ out,
                                                 float* __restrict__ dummy) {
  const int tcol4 = blockIdx.x * 64 + threadIdx.x;   // index in units of 4 columns
  const int g0    = blockIdx.y * GPB;
  const uint4* qp = qw4 + (size_t)(3 * g0) * O4 + tcol4;

  // ---- Phase 1: split-K partial (identical to R6/R9) ----
  __shared__ float xs[GPB * 32];
  const float4 xt = reinterpret_cast<const float4*>(x + g0 * 32)[threadIdx.x];
  reinterpret_cast<float4*>(xs)[threadIdx.x] = xt;

  v2f acc0 = {0.f, 0.f}, acc1 = {0.f, 0.f}, acc2 = {0.f, 0.f}, acc3 = {0.f, 0.f};

  // Rolled loop, depth-1 qweight prefetch (last iter re-loads own rows: L1 hit).
  uint4 na = qp[0], nb = qp[O4], nc = qp[2 * O4];
  for (int g = 0; g < GPB; ++g) {
    const uint4 wa = na, wb = nb, wc = nc;
    qp += (g < GPB - 1) ? 3 * O4 : 0;
    na = qp[0]; nb = qp[O4]; nc = qp[2 * O4];

    v2f xv[16];
    const float4* s4 = reinterpret_cast<const float4*>(&xs[g * 32]);
    #pragma unroll
    for (int u = 0; u < 8; ++u) {
      float4 t = s4[u];
      xv[2 * u]     = v2f{t.x, t.y};
      xv[2 * u + 1] = v2f{t.z, t.w};
    }

    dot_group_pk(wa.x, wb.x, wc.x, xv, acc0);  // 4 independent chains
    dot_group_pk(wa.y, wb.y, wc.y, xv, acc1);
    dot_group_pk(wa.z, wb.z, wc.z, xv, acc2);
    dot_group_pk(wa.w, wb.w, wc.w, xv, acc3);
  }

  float4 r = make_float4(acc0.x + acc0.y, acc1.x + acc1.y,
                         acc2.x + acc2.y, acc3.x + acc3.y);

  // ---- Epilogue: scale and accumulate directly into target (fence-free) ----
  const float4 sc = reinterpret_cast<const float4*>(scales)[tcol4];
  float4 contrib;
  contrib.x = sc.x * r.x;
  contrib.y = sc.y * r.y;
  contrib.z = sc.z * r.z;
  contrib.w = sc.w * r.w;

  if (blockIdx.y == 0) {
    // This block folds in the constant term: bias - zeros * sum(x).
    float s = 0.f;
    const float4* xall = reinterpret_cast<const float4*>(x);
    #pragma unroll
    for (int i = 0; i < (IN_FEAT / 4) / 64; ++i) {   // 32 float4 per lane
      float4 t = xall[i * 64 + threadIdx.x];
      s += (t.x + t.y) + (t.z + t.w);
    }
    #pragma unroll
    for (int off = 32; off > 0; off >>= 1) s += __shfl_xor(s, off, 64);
    const float S = s;                               // all lanes hold the total
    const float4 zr = reinterpret_cast<const float4*>(zeros)[tcol4];
    const float4 bi = reinterpret_cast<const float4*>(bias)[tcol4];
    contrib.x += bi.x - zr.x * S;
    contrib.y += bi.y - zr.y * S;
    contrib.z += bi.z - zr.z * S;
    contrib.w += bi.w - zr.w * S;
  }

  // z layers 0..3 -> dummy regions (measurement amplification); z==4 -> out.
  float* target = (blockIdx.z == NREP - 1)
                    ? out
                    : dummy + (size_t)blockIdx.z * O_FEAT;
  float* op = target + 4 * (size_t)tcol4;
  atomicAdd(op + 0, contrib.x);
  atomicAdd(op + 1, contrib.y);
  atomicAdd(op + 2, contrib.z);
  atomicAdd(op + 3, contrib.w);
}

extern "C" void kernel_launch(void* const* d_in, const int* in_sizes, int n_in,
                              void* d_out, int out_size, void* d_ws, size_t ws_size,
                              hipStream_t stream) {
  const float* x      = (const float*)d_in[0];
  const uint4* qw4    = (const uint4*)d_in[1];
  const float* scales = (const float*)d_in[2];
  const float* zeros  = (const float*)d_in[3];
  const float* bias   = (const float*)d_in[4];
  float*       out    = (float*)d_out;
  float*       dummy  = (float*)d_ws;   // 4 * O_FEAT floats = 448 KB scratch

  q3_onepass<<<dim3(NBX, SPLIT, NREP), dim3(64), 0, stream>>>(
      x, qw4, scales, zeros, bias, out, dummy);
}

// Round 12
// 142.197 us; speedup vs baseline: 1.8523x; 1.5696x over previous
//
#include <hip/hip_runtime.h>
#include <stdint.h>

// Quant3Linear GEMV: y = x @ (scales.T * unpack3(qweight) - zeros.T) + bias
//   x: (1, 8192) f32 | qweight: (768, 28672) i32 | scales,zeros: (28672,1) | bias: (28672,)
// Decomposition: y[o] = scales[o]*dot(x, q[:,o]) - zeros[o]*sum(x) + bias[o]
//
// R12: SCALAR LEAN DOT. R11's counters (first ever for this kernel): 27us/
// layer, VALUBusy 77%, occupancy-invariant, HBM 27% -> pure VALU-issue-bound
// at ~7 emitted insts/element (vs 3 ideal). Blame: v2f pair construction
// (adjacent-VGPR movs / scalarized pk_fma) + float4->v2f repack. This also
// explains R4/R5 neutrality (their savings drowned in pairing overhead).
// Fix: all-scalar dot -- per element exactly {shift, v_and_or_b32 (magic
// mantissa: code c -> 1+c/8), v_fmac_f32} = 3 VALU, no pairing, no repack.
// x pre-scaled by 8 in LDS; 8*S bias folded into epilogue (R5-verified).
// Single fence-free atomic dispatch (R9 structure).
// History: latency/TLP dead (R1,R3,R11-occ); balance dead (R6); memory dead
//   (R10: T_hot==T_cold; R11: 27% HBM); fences toxic (R8); coop fails (R7).

constexpr int O_FEAT  = 28672;
constexpr int IN_FEAT = 8192;
constexpr int NGROUP  = IN_FEAT / 32;   // 256 groups (3 packed int32 rows each)
constexpr int SPLIT   = 32;             // split-K factor
constexpr int GPB     = NGROUP / SPLIT; // 8 groups per thread
constexpr int O4      = O_FEAT / 4;     // uint4 columns per packed row
constexpr int NBX     = O4 / 64;        // 112 column groups (256 cols each)

// 3-bit field at bit sh of w -> float(1 + c/8): shift into mantissa bits
// [20:23) of 1.0f. sh is a literal after unroll -> folds to shift + and_or.
__device__ __forceinline__ float mg3(uint32_t w, int sh) {
  uint32_t u = (sh < 20) ? ((w << (20 - sh)) & 0x00700000u)
                         : ((w >> (sh - 20)) & 0x00700000u);
  return __uint_as_float(u | 0x3F800000u);
}

// Unpack one column-group (32 3-bit codes in w0,w1,w2; GPTQ packing:
// e0..9 @ w0 bits 3j; e10 split w0/w1; e11..20 @ w1 bits 3j+1; e21 split
// w1/w2; e22..31 @ w2 bits 3j+2) and accumulate dot with X=8x values.
// All scalar: 3 VALU/element, 3 chains for FMA-latency cover.
__device__ __forceinline__ void dot_group_sc(uint32_t w0, uint32_t w1, uint32_t w2,
                                             const float xv[32], float& acc) {
  float a0 = acc, a1 = 0.f, a2 = 0.f;
  #pragma unroll
  for (int j = 0; j < 10; ++j) a0 = fmaf(xv[j], mg3(w0, 3 * j), a0);
  { // e10 = (w0>>30)|((w1&1)<<2)
    uint32_t u = (((w0 >> 10) & 0x00300000u) | 0x3F800000u) | ((w1 << 22) & 0x00400000u);
    a0 = fmaf(xv[10], __uint_as_float(u), a0);
  }
  #pragma unroll
  for (int j = 0; j < 10; ++j) a1 = fmaf(xv[11 + j], mg3(w1, 3 * j + 1), a1);
  { // e21 = (w1>>31)|((w2&3)<<1)
    uint32_t u = (((w1 >> 11) & 0x00100000u) | 0x3F800000u) | ((w2 << 21) & 0x00600000u);
    a1 = fmaf(xv[21], __uint_as_float(u), a1);
  }
  #pragma unroll
  for (int j = 0; j < 10; ++j) a2 = fmaf(xv[22 + j], mg3(w2, 3 * j + 2), a2);
  acc = a0 + (a1 + a2);
}

__global__ __launch_bounds__(64) void q3_onepass(const float* __restrict__ x,
                                                 const uint4* __restrict__ qw4,
                                                 const float* __restrict__ scales,
                                                 const float* __restrict__ zeros,
                                                 const float* __restrict__ bias,
                                                 float* __restrict__ out) {
  const int tcol4 = blockIdx.x * 64 + threadIdx.x;   // index in units of 4 columns
  const int g0    = blockIdx.y * GPB;
  const uint4* qp = qw4 + (size_t)(3 * g0) * O4 + tcol4;

  // Stage this block's x chunk in LDS, PRE-SCALED by 8 (exact pow2) for the
  // magic-mantissa identity: sum 8x*(1+c/8) = 8*S_range + sum x*c.
  __shared__ float xs[GPB * 32];
  const float4 xt = reinterpret_cast<const float4*>(x + g0 * 32)[threadIdx.x];
  float4 xt8 = make_float4(8.f * xt.x, 8.f * xt.y, 8.f * xt.z, 8.f * xt.w);
  reinterpret_cast<float4*>(xs)[threadIdx.x] = xt8;

  float acc0 = 0.f, acc1 = 0.f, acc2 = 0.f, acc3 = 0.f;

  // Rolled loop, depth-1 qweight prefetch (last iter re-loads own rows: L1 hit).
  uint4 na = qp[0], nb = qp[O4], nc = qp[2 * O4];
  for (int g = 0; g < GPB; ++g) {
    const uint4 wa = na, wb = nb, wc = nc;
    qp += (g < GPB - 1) ? 3 * O4 : 0;
    na = qp[0]; nb = qp[O4]; nc = qp[2 * O4];

    float xv[32];
    const float4* s4 = reinterpret_cast<const float4*>(&xs[g * 32]);
    #pragma unroll
    for (int u = 0; u < 8; ++u) {
      float4 t = s4[u];
      xv[4 * u + 0] = t.x; xv[4 * u + 1] = t.y;
      xv[4 * u + 2] = t.z; xv[4 * u + 3] = t.w;
    }

    dot_group_sc(wa.x, wb.x, wc.x, xv, acc0);  // 4 cols x 3 chains = 12-deep ILP
    dot_group_sc(wa.y, wb.y, wc.y, xv, acc1);
    dot_group_sc(wa.z, wb.z, wc.z, xv, acc2);
    dot_group_sc(wa.w, wb.w, wc.w, xv, acc3);
  }

  // acc = 8*S_range + dot_range (per column). Scale now; bias-correct below.
  const float4 sc = reinterpret_cast<const float4*>(scales)[tcol4];
  float4 contrib;
  contrib.x = sc.x * acc0;
  contrib.y = sc.y * acc1;
  contrib.z = sc.z * acc2;
  contrib.w = sc.w * acc3;

  if (blockIdx.y == 0) {
    // Fold in bias - (8*scales + zeros) * S  (8*scales cancels magic bias).
    float s = 0.f;
    const float4* xall = reinterpret_cast<const float4*>(x);
    #pragma unroll
    for (int i = 0; i < (IN_FEAT / 4) / 64; ++i) {   // 32 float4 per lane
      float4 t = xall[i * 64 + threadIdx.x];
      s += (t.x + t.y) + (t.z + t.w);
    }
    #pragma unroll
    for (int off = 32; off > 0; off >>= 1) s += __shfl_xor(s, off, 64);
    const float S = s;                               // all lanes hold the total
    const float4 zr = reinterpret_cast<const float4*>(zeros)[tcol4];
    const float4 bi = reinterpret_cast<const float4*>(bias)[tcol4];
    contrib.x += bi.x - (8.f * sc.x + zr.x) * S;
    contrib.y += bi.y - (8.f * sc.y + zr.y) * S;
    contrib.z += bi.z - (8.f * sc.z + zr.z) * S;
    contrib.w += bi.w - (8.f * sc.w + zr.w) * S;
  }

  float* op = out + 4 * (size_t)tcol4;
  atomicAdd(op + 0, contrib.x);
  atomicAdd(op + 1, contrib.y);
  atomicAdd(op + 2, contrib.z);
  atomicAdd(op + 3, contrib.w);
}

extern "C" void kernel_launch(void* const* d_in, const int* in_sizes, int n_in,
                              void* d_out, int out_size, void* d_ws, size_t ws_size,
                              hipStream_t stream) {
  const float* x      = (const float*)d_in[0];
  const uint4* qw4    = (const uint4*)d_in[1];
  const float* scales = (const float*)d_in[2];
  const float* zeros  = (const float*)d_in[3];
  const float* bias   = (const float*)d_in[4];
  float*       out    = (float*)d_out;

  q3_onepass<<<dim3(NBX, SPLIT), dim3(64), 0, stream>>>(x, qw4, scales, zeros,
                                                        bias, out);
}